// Round 1
// baseline (145.159 us; speedup 1.0000x reference)
//
#include <hip/hip_runtime.h>
#include <math.h>

#define B_  4
#define C_  64
#define H_  128
#define W_  128
#define HW_ (H_*W_)          // 16384
#define NPIX_ (B_*HW_)       // 65536
#define GROUPS_ 32

typedef __attribute__((ext_vector_type(8))) short short8;
typedef __attribute__((ext_vector_type(4))) float f32x4;

__device__ inline short f2bf_rne(float f) {
    unsigned u = __float_as_uint(f);
    unsigned r = (u + 0x7FFFu + ((u >> 16) & 1u)) >> 16;
    return (short)r;
}
__device__ inline short8 ld8(const short* p) {
    union { uint4 u; short8 s; } c;
    c.u = *(const uint4*)p;
    return c.s;
}

// ---------------------------------------------------------------------------
// K01: blocks [0,1024): NCHW fp32 -> NHWC bf16 transpose (xtb).
//      blocks [1024,1096): composite weight prep (hi only):
//      Wcomp[cout][pos][ci] = sum_cm W2[cout][cm][pos] * W1[cm][ci], bf16.
//      couts 0-17 = off, 18-26 = mask, 27-31 = zero. Layout [32][9][64].
//      Block 1024 additionally zeroes the 256-float stats accumulator
//      (workspace is poisoned each iteration; K3 atomically accumulates).
// ---------------------------------------------------------------------------
__global__ __launch_bounds__(256) void k01(const float* __restrict__ x,
                                           const float* __restrict__ w_off1,
                                           const float* __restrict__ w_mask1,
                                           const float* __restrict__ w_off2,
                                           const float* __restrict__ w_mask2,
                                           short* __restrict__ xtb,
                                           short* __restrict__ wc_hi,
                                           float* __restrict__ stats_acc) {
    if (blockIdx.x >= 1024) {
        int i = (blockIdx.x - 1024) * 256 + threadIdx.x;   // 0..18431
        if (blockIdx.x == 1024) stats_acc[threadIdx.x] = 0.f;   // 256 floats
        if (i < 32 * 576) {
            int cout = i / 576;
            int r    = i % 576;
            int pos  = r >> 6, ci = r & 63;
            float s = 0.f;
            if (cout < 18) {
                for (int cm = 0; cm < 64; cm++)
                    s += w_off2[(cout * 64 + cm) * 9 + pos] * w_off1[cm * 64 + ci];
            } else if (cout < 27) {
                for (int cm = 0; cm < 64; cm++)
                    s += w_mask2[((cout - 18) * 64 + cm) * 9 + pos] * w_mask1[cm * 64 + ci];
            }
            wc_hi[i] = f2bf_rne(s);
        }
        return;
    }
    int l   = threadIdx.x & 63;
    int wv  = threadIdx.x >> 6;
    int row = l >> 4, col = l & 15;
    int p0  = blockIdx.x * 64 + wv * 16;
    int b   = p0 >> 14;
    int hw  = p0 & (HW_ - 1);
    const float* xb = x + (size_t)b * C_ * HW_ + hw;
#pragma unroll
    for (int kb = 0; kb < 2; kb++) {
        int ci0 = kb * 32 + row * 8;
        float xv[8];
#pragma unroll
        for (int j = 0; j < 8; j++) xv[j] = xb[(ci0 + j) * HW_ + col];
        short8 a;
#pragma unroll
        for (int j = 0; j < 8; j++) a[j] = f2bf_rne(xv[j]);
        union { short8 s; uint4 u; } cv; cv.s = a;
        *(uint4*)(xtb + ((size_t)(p0 + col)) * 64 + ci0) = cv.u;
    }
}

// ---------------------------------------------------------------------------
// K3 (fused): per-block 64-px half-row.
//   Phase A (conv): 4 waves x 16 px, MFMA 16x16x32 over K=576 against the
//     composite weights -> 27 outputs/px (18 off raw + 9 sigmoid(mask)),
//     written to LDS pom[64][28]. offmask[p] is only ever consumed by pixel
//     p, and this block owns exactly these 64 pixels -> zero redundancy vs
//     the old separate K2 dispatch, and no 16.8 MB global round-trip.
//   Phase B (gather): identical deformable bilinear gather + einsum + bias
//     -> out_pre (bf16), reading offsets/masks from LDS.
//   GroupNorm partials: block-reduced then atomicAdd into stats_acc[256]
//     (replaces the partials buffer + K4 reduce dispatch).
// XCD-band swizzle: block i -> XCD i&7; XCD x owns rows [16x,16x+16).
// ---------------------------------------------------------------------------
__global__ __launch_bounds__(256) void k3_fused(const short* __restrict__ xtb,
                                                const short* __restrict__ wc_hi,
                                                const float* __restrict__ weight,
                                                const float* __restrict__ bias,
                                                unsigned short* __restrict__ out_pre,
                                                float* __restrict__ stats_acc) {
    __shared__ float wl[C_ * 9];
    __shared__ float bl[C_];
    __shared__ float pom[64][28];            // 27 used; 28 for bank spread
    __shared__ float lds_s[4][4][8];
    __shared__ float lds_ss[4][4][8];
    for (int i = threadIdx.x; i < C_ * 9; i += 256) wl[i] = weight[i];
    if (threadIdx.x < C_) bl[threadIdx.x] = bias[threadIdx.x];

    int blk   = blockIdx.x;                  // 1024 blocks, 64 pixels each
    int xcd   = blk & 7;
    int slot  = blk >> 3;                    // 0..127
    int b     = slot >> 5;                   // image
    int r     = (slot & 31) >> 1;            // row within band
    int hrow  = slot & 1;                    // half-row
    int h     = xcd * 16 + r;

    // ---------------- Phase A: 3x3x64 conv via MFMA ----------------
    {
        int l   = threadIdx.x & 63;
        int wv  = threadIdx.x >> 6;
        int row = l >> 4, col = l & 15;
        int wA    = hrow * 64 + wv * 16 + col;        // 0..127 within row
        int pbase = b * HW_ + h * W_ + wA;            // absolute pixel

        const short8 zero8 = {0,0,0,0,0,0,0,0};
        f32x4 acc0 = {0.f,0.f,0.f,0.f};
        f32x4 acc1 = {0.f,0.f,0.f,0.f};

        short8 ca, cb0, cb1;
        {   // kb = 0: pos=0 (dy=-1,dx=-1), ci0 = row*8
            int ci0 = row * 8;
            bool valid = ((unsigned)(h - 1) < 128u) && ((unsigned)(wA - 1) < 128u);
            int addr = valid ? (pbase - 128 - 1) : pbase;
            short8 v = ld8(xtb + (size_t)addr * 64 + ci0);
            ca  = valid ? v : zero8;
            cb0 = ld8(wc_hi + (size_t)col * 576 + ci0);
            cb1 = ld8(wc_hi + (size_t)(col + 16) * 576 + ci0);
        }
#pragma unroll
        for (int kb = 0; kb < 18; kb++) {
            short8 na, nb0, nb1;
            if (kb < 17) {
                const int kn  = kb + 1;
                const int pos = kn >> 1;
                const int dy  = pos / 3 - 1, dx = pos % 3 - 1;
                int ci0 = (kn & 1) * 32 + row * 8;
                bool valid = ((unsigned)(h + dy) < 128u) && ((unsigned)(wA + dx) < 128u);
                int addr = valid ? (pbase + dy * 128 + dx) : pbase;
                short8 v = ld8(xtb + (size_t)addr * 64 + ci0);
                na  = valid ? v : zero8;
                nb0 = ld8(wc_hi + (size_t)col * 576 + pos * 64 + ci0);
                nb1 = ld8(wc_hi + (size_t)(col + 16) * 576 + pos * 64 + ci0);
            }
            acc0 = __builtin_amdgcn_mfma_f32_16x16x32_bf16(ca, cb0, acc0, 0, 0, 0);
            acc1 = __builtin_amdgcn_mfma_f32_16x16x32_bf16(ca, cb1, acc1, 0, 0, 0);
            ca = na; cb0 = nb0; cb1 = nb1;
        }

        // C layout: col = output idx (lane&15), pixel = wv*16 + (lane>>4)*4 + r
#pragma unroll
        for (int rr = 0; rr < 4; rr++) {
            int pxl = wv * 16 + row * 4 + rr;
            pom[pxl][col] = acc0[rr];                       // off 0..15
            if (col < 2)       pom[pxl][16 + col] = acc1[rr];                     // off 16,17
            else if (col < 11) pom[pxl][16 + col] = 1.f / (1.f + expf(-acc1[rr])); // mask 0..8
        }
    }
    __syncthreads();

    // ---------------- Phase B: deformable gather + einsum ----------------
    int pl    = threadIdx.x >> 2;            // 0..63 local pixel
    int chunk = threadIdx.x & 3;
    int c0    = chunk * 16;
    int w     = hrow * 64 + pl;
    int hw    = h * W_ + w;

    float acc[16];
#pragma unroll
    for (int i = 0; i < 16; i++) acc[i] = 0.f;

    const short* xb = xtb + (size_t)b * HW_ * 64;

    for (int k = 0; k < 9; k++) {
        float offy = pom[pl][2 * k];
        float offx = pom[pl][2 * k + 1];
        float mk   = pom[pl][18 + k];
        float py = offy + (float)h + (float)(k / 3 - 1);
        float px = offx + (float)w + (float)(k % 3 - 1);
        float y0f = floorf(py), x0f = floorf(px);
        int y0 = (int)y0f, x0 = (int)x0f;
        int y1 = y0 + 1,   x1 = x0 + 1;
        float wy1 = py - y0f, wx1 = px - x0f;
        float wy0 = 1.f - wy1, wx0 = 1.f - wx1;
        bool vy0 = ((unsigned)y0 < (unsigned)H_);
        bool vy1 = ((unsigned)y1 < (unsigned)H_);
        bool vx0 = ((unsigned)x0 < (unsigned)W_);
        bool vx1 = ((unsigned)x1 < (unsigned)W_);
        int cy0 = min(max(y0, 0), H_ - 1);
        int cy1 = min(max(y1, 0), H_ - 1);
        int cx0 = min(max(x0, 0), W_ - 1);
        int cx1 = min(max(x1, 0), W_ - 1);
        float b00 = wy0 * wx0 * ((vy0 && vx0) ? mk : 0.f);
        float b01 = wy0 * wx1 * ((vy0 && vx1) ? mk : 0.f);
        float b10 = wy1 * wx0 * ((vy1 && vx0) ? mk : 0.f);
        float b11 = wy1 * wx1 * ((vy1 && vx1) ? mk : 0.f);

        const short* p00 = xb + ((size_t)cy0 * W_ + cx0) * 64 + c0;
        const short* p01 = xb + ((size_t)cy0 * W_ + cx1) * 64 + c0;
        const short* p10 = xb + ((size_t)cy1 * W_ + cx0) * 64 + c0;
        const short* p11 = xb + ((size_t)cy1 * W_ + cx1) * 64 + c0;

#pragma unroll
        for (int half = 0; half < 2; half++) {
            uint4 u00 = *(const uint4*)(p00 + 8 * half);
            uint4 u01 = *(const uint4*)(p01 + 8 * half);
            uint4 u10 = *(const uint4*)(p10 + 8 * half);
            uint4 u11 = *(const uint4*)(p11 + 8 * half);
            unsigned a00[4] = {u00.x, u00.y, u00.z, u00.w};
            unsigned a01[4] = {u01.x, u01.y, u01.z, u01.w};
            unsigned a10[4] = {u10.x, u10.y, u10.z, u10.w};
            unsigned a11[4] = {u11.x, u11.y, u11.z, u11.w};
#pragma unroll
            for (int d = 0; d < 4; d++) {
                float s_lo = b00 * __uint_as_float(a00[d] << 16)
                           + b01 * __uint_as_float(a01[d] << 16)
                           + b10 * __uint_as_float(a10[d] << 16)
                           + b11 * __uint_as_float(a11[d] << 16);
                float s_hi = b00 * __uint_as_float(a00[d] & 0xFFFF0000u)
                           + b01 * __uint_as_float(a01[d] & 0xFFFF0000u)
                           + b10 * __uint_as_float(a10[d] & 0xFFFF0000u)
                           + b11 * __uint_as_float(a11[d] & 0xFFFF0000u);
                int c = 8 * half + 2 * d;
                acc[c]     += wl[(c0 + c) * 9 + k] * s_lo;
                acc[c + 1] += wl[(c0 + c + 1) * 9 + k] * s_hi;
            }
        }
    }

    // bias + bf16 store
    unsigned short* op = out_pre + ((size_t)b * C_ + c0) * HW_ + hw;
#pragma unroll
    for (int c = 0; c < 16; c++) {
        acc[c] += bl[c0 + c];
        op[c * HW_] = (unsigned short)f2bf_rne(acc[c]);
    }

    // GroupNorm partials: groups for this thread = chunk*8 + j, j=0..7
    float s8[8], ss8[8];
#pragma unroll
    for (int j = 0; j < 8; j++) {
        float a0 = acc[2 * j], a1 = acc[2 * j + 1];
        s8[j]  = a0 + a1;
        ss8[j] = a0 * a0 + a1 * a1;
    }
#pragma unroll
    for (int m = 4; m < 64; m <<= 1) {
#pragma unroll
        for (int j = 0; j < 8; j++) {
            s8[j]  += __shfl_xor(s8[j], m);
            ss8[j] += __shfl_xor(ss8[j], m);
        }
    }
    int lane = threadIdx.x & 63, wid = threadIdx.x >> 6;
    if (lane < 4) {
#pragma unroll
        for (int j = 0; j < 8; j++) {
            lds_s[wid][lane][j]  = s8[j];
            lds_ss[wid][lane][j] = ss8[j];
        }
    }
    __syncthreads();
    if (threadIdx.x < 32) {
        int g = threadIdx.x;
        int ch = g >> 3, j = g & 7;
        float S  = lds_s[0][ch][j] + lds_s[1][ch][j] + lds_s[2][ch][j] + lds_s[3][ch][j];
        float SS = lds_ss[0][ch][j] + lds_ss[1][ch][j] + lds_ss[2][ch][j] + lds_ss[3][ch][j];
        atomicAdd(&stats_acc[(b * GROUPS_ + g) * 2],     S);
        atomicAdd(&stats_acc[(b * GROUPS_ + g) * 2 + 1], SS);
    }
}

// ---------------------------------------------------------------------------
// K5: normalize + gamma/beta + exact GELU. Computes mean/rstd inline from
// the atomically-accumulated sums (K4 eliminated). Reads bf16 out_pre
// (8/thread), writes fp32 d_out.
// ---------------------------------------------------------------------------
__global__ __launch_bounds__(256) void k5_norm_gelu(const unsigned short* __restrict__ out_pre,
                                                    const float* __restrict__ stats_acc,
                                                    const float* __restrict__ gamma,
                                                    const float* __restrict__ beta,
                                                    float* __restrict__ out) {
    int i = blockIdx.x * 256 + threadIdx.x;       // 8-element index
    int e = i << 3;
    int c = (e >> 14) & (C_ - 1);
    int b = e >> 20;
    int bg = b * GROUPS_ + (c >> 1);
    float S  = stats_acc[bg * 2];
    float SS = stats_acc[bg * 2 + 1];
    const float inv = 1.f / (2.f * HW_);
    float mean = S * inv;
    float var  = SS * inv - mean * mean;
    float rstd = rsqrtf(var + 1e-5f);
    float ga = gamma[c] * rstd;
    float be = beta[c] - mean * ga;
    uint4 v = ((const uint4*)out_pre)[i];
    unsigned dw[4] = {v.x, v.y, v.z, v.w};
    float o[8];
#pragma unroll
    for (int d = 0; d < 4; d++) {
        float lo = __uint_as_float(dw[d] << 16);
        float hi = __uint_as_float(dw[d] & 0xFFFF0000u);
        float t0 = lo * ga + be;
        float t1 = hi * ga + be;
        o[2 * d]     = 0.5f * t0 * (1.f + erff(t0 * 0.70710678118654752f));
        o[2 * d + 1] = 0.5f * t1 * (1.f + erff(t1 * 0.70710678118654752f));
    }
    ((float4*)out)[2 * i]     = make_float4(o[0], o[1], o[2], o[3]);
    ((float4*)out)[2 * i + 1] = make_float4(o[4], o[5], o[6], o[7]);
}

// ---------------------------------------------------------------------------
extern "C" void kernel_launch(void* const* d_in, const int* in_sizes, int n_in,
                              void* d_out, int out_size, void* d_ws, size_t ws_size,
                              hipStream_t stream) {
    const float* x       = (const float*)d_in[0];
    const float* w_off1  = (const float*)d_in[1];
    const float* w_off2  = (const float*)d_in[2];
    const float* w_mask1 = (const float*)d_in[3];
    const float* w_mask2 = (const float*)d_in[4];
    const float* weight  = (const float*)d_in[5];
    const float* bias    = (const float*)d_in[6];
    const float* gamma   = (const float*)d_in[7];
    const float* beta    = (const float*)d_in[8];
    float* out = (float*)d_out;

    char* ws = (char*)d_ws;
    size_t o = 0;
    short* wc_hi = (short*)(ws + o); o += 32 * 576 * 2;
    o = (o + 255) & ~(size_t)255;
    short* xtb               = (short*)(ws + o);          o += (size_t)NPIX_ * 64 * 2;
    unsigned short* out_pre  = (unsigned short*)(ws + o); o += (size_t)NPIX_ * 64 * 2;
    float* stats_acc         = (float*)(ws + o);          o += 256 * 4;

    hipLaunchKernelGGL(k01, dim3(1024 + 72), dim3(256), 0, stream,
                       x, w_off1, w_mask1, w_off2, w_mask2, xtb, wc_hi, stats_acc);
    hipLaunchKernelGGL(k3_fused, dim3(NPIX_ / 64), dim3(256), 0, stream,
                       xtb, wc_hi, weight, bias, out_pre, stats_acc);
    hipLaunchKernelGGL(k5_norm_gelu, dim3(NPIX_ * 64 / 8 / 256), dim3(256), 0, stream,
                       out_pre, stats_acc, gamma, beta, out);
}